// Round 2
// baseline (172.652 us; speedup 1.0000x reference)
//
#include <hip/hip_runtime.h>

#define IN_F   100000
#define OUT_F  100000
#define NNZ_N  1600000
#define BATCH  64

// ---------------------------------------------------------------------------
// Transpose x (B=64, IN) -> x_t (IN, 64). 256-col tiles, two passes over
// batch halves (LDS 256x33 = 33.8KB). Reads: 1KB contiguous per iteration.
// Writes: 128B-coalesced chunks. ~51MB total traffic -> should be ~13us.
// ---------------------------------------------------------------------------
#define TC 256
__global__ __launch_bounds__(256) void k_transpose_x(
    const float* __restrict__ x, float* __restrict__ xt) {
    __shared__ float tile[TC][33];   // pad 33: conflict-free both phases
    const int i0 = blockIdx.x * TC;
    const int t  = threadIdx.x;      // 0..255

    #pragma unroll
    for (int p = 0; p < 2; ++p) {    // batch halves [0,32) and [32,64)
        const int b0 = p * 32;
        const int colr = i0 + t;
        if (colr < IN_F) {
            #pragma unroll 8
            for (int bb = 0; bb < 32; ++bb)
                tile[t][bb] = x[(size_t)(b0 + bb) * IN_F + colr];
        }
        __syncthreads();
        // write: thread t -> batch b32 = t&31, column lane cl = t>>5 (8 cols/iter)
        const int b32 = t & 31;
        const int cl  = t >> 5;
        for (int ccb = 0; ccb < TC; ccb += 8) {
            const int cc  = ccb + cl;
            const int col = i0 + cc;
            if (col < IN_F)
                xt[(size_t)col * 64 + b0 + b32] = tile[cc][b32];
        }
        __syncthreads();
    }
}

// ---------------------------------------------------------------------------
// SpMM from x_t. Block = 512 threads (8 waves) handles 64 consecutive rows;
// each wave handles 8 rows. Within a wave: lane = (g = lane>>4 edge-slot,
// sub = lane&15 batch-quad). Each gather instruction = float4/lane = 1KB =
// 4 edges in one shot; 4 such instructions in flight per 16-edge chunk.
// Row totals reduced across the 4 g-groups via shfl_xor(16|32).
// ---------------------------------------------------------------------------
__global__ __launch_bounds__(512, 8) void k_spmm_t(
    const float* __restrict__ xt,
    const float* __restrict__ vals,
    const int*   __restrict__ rows,
    const int*   __restrict__ cols,
    const float* __restrict__ bias,
    float* __restrict__ out) {
    __shared__ int   rstart[65];
    __shared__ float tile[64][65];       // [local_row][batch], padded

    const int r0   = blockIdx.x * 64;
    const int t    = threadIdx.x;
    const int lane = t & 63;
    const int w    = t >> 6;             // 0..7

    if (t < 65) {
        const int target = r0 + t;
        int lo = 0, hi = NNZ_N;
        while (lo < hi) {
            const int mid = (lo + hi) >> 1;
            if (rows[mid] < target) lo = mid + 1; else hi = mid;
        }
        rstart[t] = lo;
    }
    __syncthreads();

    const int g   = lane >> 4;           // which of 4 edges per instruction
    const int sub = lane & 15;           // batch quad: batches 4*sub..4*sub+3

    for (int j = w; j < 64; j += 8) {
        const int s = rstart[j];
        const int e = rstart[j + 1];
        float4 acc = {0.f, 0.f, 0.f, 0.f};

        for (int base = s; base < e; base += 16) {   // 16 edges per chunk
            #pragma unroll
            for (int k = 0; k < 4; ++k) {
                const int idx = base + 4 * k + g;
                const int ci  = (idx < e) ? idx : (e - 1);
                const int c   = cols[ci];
                const float v = (idx < e) ? vals[idx] : 0.f;
                const float4 xv = *(const float4*)(xt + (size_t)c * 64 + 4 * sub);
                acc.x = fmaf(v, xv.x, acc.x);
                acc.y = fmaf(v, xv.y, acc.y);
                acc.z = fmaf(v, xv.z, acc.z);
                acc.w = fmaf(v, xv.w, acc.w);
            }
        }
        // reduce the 4 g-groups (xor 16 then 32 preserves sub)
        acc.x += __shfl_xor(acc.x, 16); acc.x += __shfl_xor(acc.x, 32);
        acc.y += __shfl_xor(acc.y, 16); acc.y += __shfl_xor(acc.y, 32);
        acc.z += __shfl_xor(acc.z, 16); acc.z += __shfl_xor(acc.z, 32);
        acc.w += __shfl_xor(acc.w, 16); acc.w += __shfl_xor(acc.w, 32);
        if (g == 0) {
            float* trow = &tile[j][4 * sub];
            trow[0] = acc.x; trow[1] = acc.y; trow[2] = acc.z; trow[3] = acc.w;
        }
    }
    __syncthreads();

    // write phase: out[b*OUT + r0 + c] coalesced (256B per wave), + bias
    const int c  = lane;
    const int rc = r0 + c;
    if (rc < OUT_F) {
        const float bv = bias[rc];
        for (int bb = w; bb < 64; bb += 8)
            out[(size_t)bb * OUT_F + rc] = tile[c][bb] + bv;
    }
}

// ---------------------------------------------------------------------------
// Fallback (no workspace): scalar gather from native x layout. Correct, slow.
// ---------------------------------------------------------------------------
__global__ __launch_bounds__(256) void k_spmm_fallback(
    const float* __restrict__ x,
    const float* __restrict__ vals,
    const int*   __restrict__ rows,
    const int*   __restrict__ cols,
    const float* __restrict__ bias,
    float* __restrict__ out) {
    __shared__ int   rstart[65];
    __shared__ float tile[64][65];
    const int r0   = blockIdx.x * 64;
    const int t    = threadIdx.x;
    const int lane = t & 63;
    const int w    = t >> 6;
    if (t < 65) {
        const int target = r0 + t;
        int lo = 0, hi = NNZ_N;
        while (lo < hi) {
            const int mid = (lo + hi) >> 1;
            if (rows[mid] < target) lo = mid + 1; else hi = mid;
        }
        rstart[t] = lo;
    }
    __syncthreads();
    for (int j = w; j < 64; j += 4) {
        const int s = rstart[j], e = rstart[j + 1];
        float acc = 0.f;
        const size_t base = (size_t)lane * IN_F;
        for (int idx = s; idx < e; ++idx)
            acc = fmaf(vals[idx], x[base + cols[idx]], acc);
        tile[j][lane] = acc;
    }
    __syncthreads();
    const int c = lane;
    if (r0 + c < OUT_F) {
        const float bv = bias[r0 + c];
        for (int bb = w; bb < 64; bb += 4)
            out[(size_t)bb * OUT_F + (r0 + c)] = tile[c][bb] + bv;
    }
}

extern "C" void kernel_launch(void* const* d_in, const int* in_sizes, int n_in,
                              void* d_out, int out_size, void* d_ws, size_t ws_size,
                              hipStream_t stream) {
    const float* x      = (const float*)d_in[0];
    const float* values = (const float*)d_in[1];
    const float* bias   = (const float*)d_in[2];
    const int*   rows   = (const int*)d_in[3];
    const int*   cols   = (const int*)d_in[4];
    float*       out    = (float*)d_out;

    const size_t xt_bytes  = (size_t)IN_F * 64 * sizeof(float);  // 25.6 MB
    const int    row_blocks = (OUT_F + 63) / 64;                 // 1563
    const int    tc_blocks  = (IN_F + TC - 1) / TC;              // 391

    if (ws_size >= xt_bytes) {
        float* xt = (float*)d_ws;
        k_transpose_x<<<tc_blocks, 256, 0, stream>>>(x, xt);
        k_spmm_t<<<row_blocks, 512, 0, stream>>>(xt, values, rows, cols, bias, out);
    } else {
        k_spmm_fallback<<<row_blocks, 256, 0, stream>>>(x, values, rows, cols, bias, out);
    }
}

// Round 3
// 142.728 us; speedup vs baseline: 1.2097x; 1.2097x over previous
//
#include <hip/hip_runtime.h>
#include <hip/hip_fp16.h>

#define IN_F   100000
#define OUT_F  100000
#define NNZ_N  1600000

// ---------------------------------------------------------------------------
// Kernel A: x (B=64, IN) f32 -> xh (IN, 64) f16.  256-col tiles, single pass.
// Reads 256B-coalesced; LDS holds packed half2; writes 256B-contiguous
// (one wave writes 2 full 128B rows of xh per instruction).
// ---------------------------------------------------------------------------
#define TC 256
__global__ __launch_bounds__(256) void k_x_to_half_t(
    const float* __restrict__ x, __half* __restrict__ xh) {
    __shared__ unsigned tile[TC][33];   // [col][batch_pair], packed half2; pad 33
    const int i0 = blockIdx.x * TC;
    const int t  = threadIdx.x;
    const int colr = i0 + t;

    if (colr < IN_F) {
        #pragma unroll 4
        for (int p = 0; p < 32; ++p) {          // batch pair p -> batches 2p, 2p+1
            const float a = x[(size_t)(2 * p)     * IN_F + colr];
            const float b = x[(size_t)(2 * p + 1) * IN_F + colr];
            const __half2 h = __floats2half2_rn(a, b);   // .x=a(low), .y=b(high)
            tile[t][p] = *reinterpret_cast<const unsigned*>(&h);
        }
    }
    __syncthreads();

    // write: lane u = t&31 indexes batch-pair, wave covers 2 adjacent cols
    const int u  = t & 31;
    const int c8 = t >> 5;                      // 0..7 across block
    unsigned* xhu = reinterpret_cast<unsigned*>(xh);
    for (int cc = c8; cc < TC; cc += 8) {
        const int col = i0 + cc;
        if (col < IN_F)
            xhu[(size_t)col * 32 + u] = tile[cc][u];
    }
}

// ---------------------------------------------------------------------------
// Kernel B: row segment starts. rstart[r] = lower_bound(rows, r), r in [0,OUT_F].
// ---------------------------------------------------------------------------
__global__ __launch_bounds__(256) void k_rowstart(
    const int* __restrict__ rows, int* __restrict__ rstart) {
    const int r = blockIdx.x * 256 + threadIdx.x;
    if (r > OUT_F) return;
    int lo = 0, hi = NNZ_N;
    while (lo < hi) {
        const int mid = (lo + hi) >> 1;
        if (rows[mid] < r) lo = mid + 1; else hi = mid;
    }
    rstart[r] = lo;
}

// ---------------------------------------------------------------------------
// Kernel C: SpMM from fp16 x_t. Block = 512 threads (8 waves) -> 64 rows.
// Each 16-lane group (g = lane>>4) OWNS whole rows (2 per group): no
// cross-group reduction. Lane sub = lane&15 covers batches 4sub..4sub+3
// via one 8B load (4 halves) per edge; 4 edges unrolled per chunk -> 16
// independent gathers in flight per wave. fp32 accumulate.
// ---------------------------------------------------------------------------
__device__ __forceinline__ float2 h2f(unsigned u) {
    const __half2 h = *reinterpret_cast<const __half2*>(&u);
    return __half22float2(h);
}

__global__ __launch_bounds__(512, 8) void k_spmm_h(
    const __half* __restrict__ xh,
    const float*  __restrict__ vals,
    const int*    __restrict__ cols,
    const int*    __restrict__ rstart_g,
    const float*  __restrict__ bias,
    float* __restrict__ out) {
    __shared__ int   rs[65];
    __shared__ float tile[64][65];
    const int r0   = blockIdx.x * 64;
    const int t    = threadIdx.x;
    const int lane = t & 63;
    const int w    = t >> 6;

    if (t < 65) {
        int idx = r0 + t; if (idx > OUT_F) idx = OUT_F;
        rs[t] = rstart_g[idx];
    }
    __syncthreads();

    const int g   = lane >> 4;
    const int sub = lane & 15;
    const __half* xb = xh + (sub << 2);     // batches 4sub..4sub+3

    #pragma unroll
    for (int r = 0; r < 2; ++r) {
        const int lj = (w << 3) + (r << 2) + g;   // local row, unique in [0,64)
        const int s = rs[lj];
        const int e = rs[lj + 1];
        float4 acc = {0.f, 0.f, 0.f, 0.f};

        for (int base = s; base < e; base += 4) {
            const int e1 = e - 1;
            const int i1 = (base + 1 < e) ? base + 1 : e1;
            const int i2 = (base + 2 < e) ? base + 2 : e1;
            const int i3 = (base + 3 < e) ? base + 3 : e1;
            const int c0 = cols[base], c1 = cols[i1], c2 = cols[i2], c3 = cols[i3];
            const float v0 = vals[base];
            float v1 = vals[i1]; if (base + 1 >= e) v1 = 0.f;
            float v2 = vals[i2]; if (base + 2 >= e) v2 = 0.f;
            float v3 = vals[i3]; if (base + 3 >= e) v3 = 0.f;
            const uint2 u0 = *(const uint2*)(xb + ((size_t)c0 << 6));
            const uint2 u1 = *(const uint2*)(xb + ((size_t)c1 << 6));
            const uint2 u2 = *(const uint2*)(xb + ((size_t)c2 << 6));
            const uint2 u3 = *(const uint2*)(xb + ((size_t)c3 << 6));
            float2 f;
            f = h2f(u0.x); acc.x = fmaf(v0, f.x, acc.x); acc.y = fmaf(v0, f.y, acc.y);
            f = h2f(u0.y); acc.z = fmaf(v0, f.x, acc.z); acc.w = fmaf(v0, f.y, acc.w);
            f = h2f(u1.x); acc.x = fmaf(v1, f.x, acc.x); acc.y = fmaf(v1, f.y, acc.y);
            f = h2f(u1.y); acc.z = fmaf(v1, f.x, acc.z); acc.w = fmaf(v1, f.y, acc.w);
            f = h2f(u2.x); acc.x = fmaf(v2, f.x, acc.x); acc.y = fmaf(v2, f.y, acc.y);
            f = h2f(u2.y); acc.z = fmaf(v2, f.x, acc.z); acc.w = fmaf(v2, f.y, acc.w);
            f = h2f(u3.x); acc.x = fmaf(v3, f.x, acc.x); acc.y = fmaf(v3, f.y, acc.y);
            f = h2f(u3.y); acc.z = fmaf(v3, f.x, acc.z); acc.w = fmaf(v3, f.y, acc.w);
        }
        // each row written by exactly one 16-lane group; scalar b32 writes
        // keep the epilogue reads (stride 65) conflict-free
        const int co = sub << 2;
        tile[lj][co + 0] = acc.x;
        tile[lj][co + 1] = acc.y;
        tile[lj][co + 2] = acc.z;
        tile[lj][co + 3] = acc.w;
    }
    __syncthreads();

    const int rc = r0 + lane;
    if (rc < OUT_F) {
        const float bv = bias[rc];
        for (int bb = w; bb < 64; bb += 8)
            out[(size_t)bb * OUT_F + rc] = tile[lane][bb] + bv;
    }
}

// ---------------------------------------------------------------------------
// Fallback (insufficient ws): gather from native x layout. Correct, slow.
// ---------------------------------------------------------------------------
__global__ __launch_bounds__(256) void k_spmm_fallback(
    const float* __restrict__ x,
    const float* __restrict__ vals,
    const int*   __restrict__ rows,
    const int*   __restrict__ cols,
    const float* __restrict__ bias,
    float* __restrict__ out) {
    __shared__ int   rstart[65];
    __shared__ float tile[64][65];
    const int r0   = blockIdx.x * 64;
    const int t    = threadIdx.x;
    const int lane = t & 63;
    const int w    = t >> 6;
    if (t < 65) {
        const int target = r0 + t;
        int lo = 0, hi = NNZ_N;
        while (lo < hi) {
            const int mid = (lo + hi) >> 1;
            if (rows[mid] < target) lo = mid + 1; else hi = mid;
        }
        rstart[t] = lo;
    }
    __syncthreads();
    for (int j = w; j < 64; j += 4) {
        const int s = rstart[j], e = rstart[j + 1];
        float acc = 0.f;
        const size_t base = (size_t)lane * IN_F;
        for (int idx = s; idx < e; ++idx)
            acc = fmaf(vals[idx], x[base + cols[idx]], acc);
        tile[j][lane] = acc;
    }
    __syncthreads();
    const int c = lane;
    if (r0 + c < OUT_F) {
        const float bv = bias[r0 + c];
        for (int bb = w; bb < 64; bb += 4)
            out[(size_t)bb * OUT_F + (r0 + c)] = tile[c][bb] + bv;
    }
}

extern "C" void kernel_launch(void* const* d_in, const int* in_sizes, int n_in,
                              void* d_out, int out_size, void* d_ws, size_t ws_size,
                              hipStream_t stream) {
    const float* x      = (const float*)d_in[0];
    const float* values = (const float*)d_in[1];
    const float* bias   = (const float*)d_in[2];
    const int*   rows   = (const int*)d_in[3];
    const int*   cols   = (const int*)d_in[4];
    float*       out    = (float*)d_out;

    const size_t xh_bytes = (size_t)IN_F * 64 * sizeof(__half);      // 12.8 MB
    const size_t rs_off   = (xh_bytes + 255) & ~(size_t)255;
    const size_t need     = rs_off + (size_t)(OUT_F + 1) * sizeof(int);

    const int row_blocks = (OUT_F + 63) / 64;          // 1563
    const int tc_blocks  = (IN_F + TC - 1) / TC;       // 391
    const int rs_blocks  = (OUT_F + 1 + 255) / 256;    // 392

    if (ws_size >= need) {
        __half* xh     = (__half*)d_ws;
        int*    rstart = (int*)((char*)d_ws + rs_off);
        k_x_to_half_t<<<tc_blocks, 256, 0, stream>>>(x, xh);
        k_rowstart<<<rs_blocks, 256, 0, stream>>>(rows, rstart);
        k_spmm_h<<<row_blocks, 512, 0, stream>>>(xh, values, cols, rstart, bias, out);
    } else {
        k_spmm_fallback<<<row_blocks, 256, 0, stream>>>(x, values, rows, cols, bias, out);
    }
}